// Round 13
// baseline (524.060 us; speedup 1.0000x reference)
//
#include <hip/hip_runtime.h>
#include <hip/hip_bf16.h>
#include <math.h>

#define BATCH 4
#define SEQ 4096
#define ROWS 16384
#define DIN 1024
#define DMODEL 512
#define DINNER 1024
#define DSTATE 64
#define NH 16
#define HD 64
#define CONVDIM 1152              /* DINNER + 2*DSTATE */
#define DPROJ 2192                /* 2*DINNER + 2*DSTATE + NH */
#define NPAD 2304                 /* DPROJ padded to x128 */
#define QC 64                     /* SSD chunk length */
#define NCH 64                    /* SEQ/QC chunks per batch */
#define LD 72                     /* LDS tile stride (bf16 elems) */

typedef __attribute__((ext_vector_type(8))) __bf16 bf16x8;
typedef __attribute__((ext_vector_type(4))) __bf16 bf16x4;
typedef __attribute__((ext_vector_type(4))) float f32x4;

__device__ __forceinline__ float siluf(float x){ return x / (1.f + __expf(-x)); }
__device__ __forceinline__ float geluf(float x){ return 0.5f*x*(1.f + erff(x*0.70710678118654752440f)); }

__device__ __forceinline__ bf16x8 scale8(bf16x8 v, float s){
  bf16x8 r;
  #pragma unroll
  for (int e = 0; e < 8; e++) r[e] = (__bf16)((float)v[e]*s);
  return r;
}

/* async global->LDS, 16B per lane; lds base must be wave-uniform */
__device__ __forceinline__ void gl_lds16(const void* g, void* l){
  __builtin_amdgcn_global_load_lds((const __attribute__((address_space(1))) void*)g,
                                   (__attribute__((address_space(3))) void*)l, 16, 0, 0);
}

__device__ __forceinline__ bf16x8 cvt8(const float* sp){
  const float4* p = (const float4*)sp;
  float4 a = p[0], b = p[1];
  bf16x8 o;
  o[0]=(__bf16)a.x; o[1]=(__bf16)a.y; o[2]=(__bf16)a.z; o[3]=(__bf16)a.w;
  o[4]=(__bf16)b.x; o[5]=(__bf16)b.y; o[6]=(__bf16)b.z; o[7]=(__bf16)b.w;
  return o;
}

/* ---------------- prep: vectorized x cast ---------------- */
__global__ void cast_bf16_kernel(const float* __restrict__ src, __bf16* __restrict__ dst, long n8){
  long i = (long)blockIdx.x*blockDim.x + threadIdx.x;
  long stride = (long)gridDim.x*blockDim.x;
  for (; i < n8; i += stride) *(bf16x8*)(dst + i*8) = cvt8(src + i*8);
}

/* ---------------- merged weight prep: W1, W_out, W_in(padded) ---------------- */
#define W1G   (DMODEL*DIN/8)            /* 65536  */
#define WOG   (2*DMODEL*DINNER/8)       /* 131072 */
#define WIG   (2L*NPAD*(DMODEL/8))      /* 294912 */
__global__ void prep_weights(const float* __restrict__ W1, const float* __restrict__ W_out,
                             const float* __restrict__ W_in, __bf16* __restrict__ W1b,
                             __bf16* __restrict__ Woutb, __bf16* __restrict__ Winb){
  long total = W1G + WOG + WIG;
  long i = (long)blockIdx.x*blockDim.x + threadIdx.x;
  long stride = (long)gridDim.x*blockDim.x;
  for (; i < total; i += stride){
    if (i < W1G){
      *(bf16x8*)(W1b + i*8) = cvt8(W1 + i*8);
    } else if (i < W1G + WOG){
      long j = i - W1G;
      *(bf16x8*)(Woutb + j*8) = cvt8(W_out + j*8);
    } else {
      long j = i - W1G - WOG;
      int k8 = (int)(j % (DMODEL/8));
      int n  = (int)((j / (DMODEL/8)) % NPAD);
      int l  = (int)(j / ((long)(DMODEL/8)*NPAD));
      bf16x8 o;
      if (n < DPROJ){
        o = cvt8(W_in + ((long)l*DPROJ + n)*DMODEL + k8*8);
      } else {
        #pragma unroll
        for (int e = 0; e < 8; e++) o[e] = (__bf16)0.f;
      }
      *(bf16x8*)(Winb + ((long)l*NPAD + n)*DMODEL + k8*8) = o;
    }
  }
}

/* ---------------- GEMM (4-wave, BMxBN, BK=32): NBUF-ring, prefetch depth NBUF-1. ---------------- */
template<typename OutT, int EPI, int BM, int BN, int NBUF>
__global__ __launch_bounds__(256) void gemm_bt(const __bf16* __restrict__ A, const __bf16* __restrict__ Bm,
                                               OutT* __restrict__ C, const float* __restrict__ bias,
                                               int K, int Nc){
  constexpr int MI = BM/32, NI = BN/32;
  constexpr int CHA = BM/64;
  constexpr int CHT = (BM+BN)/64;
  constexpr int DEPTH = NBUF - 1;
  __shared__ __align__(16) __bf16 As[NBUF][BM*32];
  __shared__ __align__(16) __bf16 Bs[NBUF][BN*32];
  int bm = blockIdx.x, bn = blockIdx.y;
  int tid = threadIdx.x;
  int lane = tid & 63, wid = tid >> 6;
  int wm = (wid >> 1)*(BM/2), wn = (wid & 1)*(BN/2);
  int lr = lane & 15, kb = lane >> 4;
  f32x4 acc[MI][NI] = {};
  const char* Ab = (const char*)A + (size_t)bm*BM*(size_t)(K*2);
  const char* Bb = (const char*)Bm + (size_t)bn*BN*(size_t)(K*2);
  int nkk = K >> 5;

  auto STAGE = [&](int kk, int buf){
    #pragma unroll
    for (int it = 0; it < CHT; it++){
      int cbase = it*4096 + wid*1024;
      int off = cbase + lane*16;
      int row = off >> 6, cb = off & 63;
      if (it < CHA) gl_lds16(Ab + (size_t)row*(K*2) + kk*64 + cb, (char*)(&As[buf][0]) + cbase);
      else          gl_lds16(Bb + (size_t)(row - BM)*(K*2) + kk*64 + cb, (char*)(&Bs[buf][0]) + (cbase - BM*64));
    }
  };

  #pragma unroll
  for (int i = 0; i < DEPTH; i++) if (i < nkk) STAGE(i, i);
  for (int kk = 0; kk < nkk; kk++){
    int cur = kk % NBUF;
    int rem = nkk - 1 - kk;
    if (rem >= DEPTH){
      STAGE(kk + DEPTH, (kk + DEPTH) % NBUF);
      asm volatile("s_waitcnt vmcnt(%0)" :: "n"(DEPTH*CHT) : "memory");
    } else if (DEPTH > 2 && rem == 2){
      asm volatile("s_waitcnt vmcnt(%0)" :: "n"(2*CHT) : "memory");
    } else if (rem == 1){
      asm volatile("s_waitcnt vmcnt(%0)" :: "n"(CHT) : "memory");
    } else {
      asm volatile("s_waitcnt vmcnt(0)" ::: "memory");
    }
    __builtin_amdgcn_sched_barrier(0);
    __builtin_amdgcn_s_barrier();
    __builtin_amdgcn_sched_barrier(0);
    const __bf16* Asb = &As[cur][0];
    const __bf16* Bsb = &Bs[cur][0];
    bf16x8 af[MI], bfr[NI];
    #pragma unroll
    for (int mi = 0; mi < MI; mi++) af[mi] = *(const bf16x8*)(Asb + (wm + mi*16 + lr)*32 + kb*8);
    #pragma unroll
    for (int ni = 0; ni < NI; ni++) bfr[ni] = *(const bf16x8*)(Bsb + (wn + ni*16 + lr)*32 + kb*8);
    #pragma unroll
    for (int mi = 0; mi < MI; mi++)
      #pragma unroll
      for (int ni = 0; ni < NI; ni++)
        acc[mi][ni] = __builtin_amdgcn_mfma_f32_16x16x32_bf16(af[mi], bfr[ni], acc[mi][ni], 0, 0, 0);
    __builtin_amdgcn_s_barrier();
    __builtin_amdgcn_sched_barrier(0);
  }
  #pragma unroll
  for (int mi = 0; mi < MI; mi++){
    #pragma unroll
    for (int ni = 0; ni < NI; ni++){
      int r0 = bm*BM + wm + mi*16 + (lane >> 4)*4;
      int c  = bn*BN + wn + ni*16 + lr;
      if (c < Nc){
        OutT* Cp = C + (size_t)r0*Nc + c;
        #pragma unroll
        for (int j = 0; j < 4; j++){
          float v = acc[mi][ni][j];
          if (EPI == 1){ float u = v + bias[c]; v = geluf(u); }
          if (EPI == 2){ v += (float)Cp[(size_t)j*Nc]; }
          Cp[(size_t)j*Nc] = (OutT)v;
        }
      }
    }
  }
}

/* ---------------- LayerNorm row(512) bf16 -> bf16 ---------------- */
__global__ __launch_bounds__(256) void ln_kernel(const __bf16* __restrict__ h, const float* __restrict__ w,
                                                 const float* __restrict__ b, __bf16* __restrict__ out){
  int row = blockIdx.x*4 + (threadIdx.x >> 6);
  int lane = threadIdx.x & 63;
  const __bf16* hr = h + (size_t)row*DMODEL + lane*8;
  bf16x8 a = *(const bf16x8*)hr;
  float v[8];
  #pragma unroll
  for (int i = 0; i < 8; i++) v[i] = (float)a[i];
  float s = 0.f;
  #pragma unroll
  for (int i = 0; i < 8; i++) s += v[i];
  #pragma unroll
  for (int o = 32; o; o >>= 1) s += __shfl_xor(s, o, 64);
  float mu = s*(1.f/512.f);
  float q = 0.f;
  #pragma unroll
  for (int i = 0; i < 8; i++){ float d = v[i]-mu; q += d*d; }
  #pragma unroll
  for (int o = 32; o; o >>= 1) q += __shfl_xor(q, o, 64);
  float rs = rsqrtf(q*(1.f/512.f) + 1e-5f);
  const float* wp = w + lane*8; const float* bp = b + lane*8;
  bf16x8 o8;
  #pragma unroll
  for (int i = 0; i < 8; i++) o8[i] = (__bf16)((v[i]-mu)*rs*wp[i] + bp[i]);
  *(bf16x8*)(out + (size_t)row*DMODEL + lane*8) = o8;
}

/* ---------------- merged conv+SiLU (B/C channels) and dt=softplus ---------------- */
__global__ __launch_bounds__(256) void convdt_kernel(const __bf16* __restrict__ zx, const float* __restrict__ cw,
                                                     const float* __restrict__ cb, const float* __restrict__ dt_bias,
                                                     __bf16* __restrict__ BCc, float* __restrict__ dtT){
  long idx = (long)blockIdx.x*256 + threadIdx.x;   /* ROWS*144 */
  long bt = idx / 144;
  int j = (int)(idx - bt*144);
  if (bt >= ROWS) return;
  int t = (int)(bt & (SEQ-1));
  int b = (int)(bt >> 12);
  if (j < 128){
    int ch = DINNER + j;
    const __bf16* src = zx + (size_t)bt*DPROJ + 2048 + j;
    float acc = cb[ch] + (float)src[0]*cw[ch*4+3];
    if (t >= 1) acc += (float)src[-1L*DPROJ]*cw[ch*4+2];
    if (t >= 2) acc += (float)src[-2L*DPROJ]*cw[ch*4+1];
    if (t >= 3) acc += (float)src[-3L*DPROJ]*cw[ch*4+0];
    BCc[(size_t)bt*128 + j] = (__bf16)siluf(acc);
  } else {
    int hh = j - 128;
    float v = (float)zx[(size_t)bt*DPROJ + (DPROJ-NH) + hh] + dt_bias[hh];
    float sp = (v > 20.f) ? v : log1pf(__expf(v));
    dtT[((size_t)b*NH + hh)*SEQ + t] = sp;
  }
}

/* ================= SSD kernel A — per-chunk state via MFMA (2 waves/block) ================= */
__global__ __launch_bounds__(128) void ssd_state(const __bf16* __restrict__ zx, const __bf16* __restrict__ BCc,
                                                 const float* __restrict__ dtT, const float* __restrict__ A_log,
                                                 const float* __restrict__ cw, const float* __restrict__ cb,
                                                 __bf16* __restrict__ Schunk, float* __restrict__ Pbuf,
                                                 __bf16* __restrict__ xhT){
  __shared__ __align__(16) __bf16 Bt_all[2][64*LD];
  __shared__ __align__(16) __bf16 Xt_all[2][64*LD];
  int widx = threadIdx.x >> 6, lane = threadIdx.x & 63;
  int c = blockIdx.x*2 + widx, h = blockIdx.y, b = blockIdx.z;
  __bf16* Bt = Bt_all[widx];
  __bf16* Xt = Xt_all[widx];
  int lr = lane & 15, kb = lane >> 4, hi4 = lane >> 4;
  long t0 = (long)c*QC;
  size_t bt0 = (size_t)b*SEQ + t0;
  int bh = b*NH + h;
  float Ac = -expf(A_log[h]);
  float dtv = dtT[(size_t)bh*SEQ + t0 + lane];
  float cum = dtv*Ac;
  #pragma unroll
  for (int off = 1; off < 64; off <<= 1){ float v = __shfl_up(cum, off, 64); if (lane >= off) cum += v; }
  float cumQ = __shfl(cum, 63, 64);
  float w = __expf(cumQ - cum) * dtv;
  {
    const __bf16* bp = BCc + bt0*128 + lane;
    for (int tb = 0; tb < 8; tb++){
      bf16x8 buf;
      #pragma unroll
      for (int u = 0; u < 8; u++){
        int t = tb*8 + u;
        float bv = (float)bp[(size_t)t*128];
        buf[u] = (__bf16)(bv * __shfl(w, t, 64));
      }
      *(bf16x8*)&Bt[lane*LD + tb*8] = buf;
    }
  }
  {
    int ch = h*HD + lane;
    float w0 = cw[ch*4], w1 = cw[ch*4+1], w2 = cw[ch*4+2], w3 = cw[ch*4+3], cbv = cb[ch];
    const __bf16* xp = zx + bt0*DPROJ + (DINNER + ch);
    float x1 = (t0 >= 1) ? (float)xp[-1L*DPROJ] : 0.f;
    float x2 = (t0 >= 2) ? (float)xp[-2L*DPROJ] : 0.f;
    float x3 = (t0 >= 3) ? (float)xp[-3L*DPROJ] : 0.f;
    __bf16* xo = xhT + ((size_t)bh*NCH + c)*4096 + lane*64;
    for (int tb = 0; tb < 8; tb++){
      bf16x8 buf;
      #pragma unroll
      for (int u = 0; u < 8; u++){
        int t = tb*8 + u;
        float x0 = (float)xp[(size_t)t*DPROJ];
        float xv = siluf(cbv + w3*x0 + w2*x1 + w1*x2 + w0*x3);
        x3 = x2; x2 = x1; x1 = x0;
        buf[u] = (__bf16)xv;
      }
      *(bf16x8*)&Xt[lane*LD + tb*8] = buf;
      *(bf16x8*)(xo + tb*8) = buf;
    }
  }
  f32x4 acc[4][4] = {};
  #pragma unroll
  for (int kk = 0; kk < 2; kk++){
    bf16x8 af[4], bfr[4];
    #pragma unroll
    for (int mi = 0; mi < 4; mi++) af[mi]  = *(bf16x8*)&Bt[(mi*16+lr)*LD + kk*32 + kb*8];
    #pragma unroll
    for (int ni = 0; ni < 4; ni++) bfr[ni] = *(bf16x8*)&Xt[(ni*16+lr)*LD + kk*32 + kb*8];
    #pragma unroll
    for (int mi = 0; mi < 4; mi++)
      #pragma unroll
      for (int ni = 0; ni < 4; ni++)
        acc[mi][ni] = __builtin_amdgcn_mfma_f32_16x16x32_bf16(af[mi], bfr[ni], acc[mi][ni], 0, 0, 0);
  }
  __bf16* Sp = Schunk + ((size_t)bh*NCH + c)*4096;
  #pragma unroll
  for (int mi = 0; mi < 4; mi++)
    #pragma unroll
    for (int ni = 0; ni < 4; ni++){
      int n0 = mi*16 + hi4*4;
      int p  = ni*16 + lr;
      bf16x4 v;
      #pragma unroll
      for (int r = 0; r < 4; r++) v[r] = (__bf16)acc[mi][ni][r];
      *(bf16x4*)&Sp[p*64 + n0] = v;
    }
  if (lane == 0) Pbuf[bh*NCH + c] = __expf(cumQ);
}

/* ========== in-place chunk-state -> prefix-state ========== */
__global__ __launch_bounds__(64) void ssd_comb(__bf16* __restrict__ Schunk, const float* __restrict__ Pbuf){
  int bh = blockIdx.x >> 4;
  int eb = blockIdx.x & 15;
  int e = eb*256 + threadIdx.x*4;
  __bf16* base = Schunk + (size_t)bh*NCH*4096 + e;
  float T0 = 0.f, T1 = 0.f, T2 = 0.f, T3 = 0.f;
  for (int c = 0; c < NCH; c++){
    float P = Pbuf[bh*NCH + c];
    bf16x4* p = (bf16x4*)(base + (size_t)c*4096);
    bf16x4 s = *p;
    bf16x4 o; o[0] = (__bf16)T0; o[1] = (__bf16)T1; o[2] = (__bf16)T2; o[3] = (__bf16)T3;
    *p = o;
    T0 = T0*P + (float)s[0]; T1 = T1*P + (float)s[1];
    T2 = T2*P + (float)s[2]; T3 = T3*P + (float)s[3];
  }
}

/* ================= SSD kernel B — outputs via MFMA (4 waves/block, per-wave LDS) ================= */
__global__ __launch_bounds__(256) void ssd_y(const __bf16* __restrict__ BCc, const float* __restrict__ dtT,
                                             const float* __restrict__ A_log, const float* __restrict__ Dskip,
                                             const __bf16* __restrict__ xhT, const __bf16* __restrict__ Spre,
                                             __bf16* __restrict__ yout){
  __shared__ __align__(16) __bf16 Gs_all[4][64*LD];
  __shared__ float cum_all[4][64], dt_all[4][64];
  int widx = threadIdx.x >> 6, lane = threadIdx.x & 63;
  int c = blockIdx.x*4 + widx, h = blockIdx.y, b = blockIdx.z;
  __bf16* Gs = Gs_all[widx];
  float* cum_s = cum_all[widx];
  float* dt_s = dt_all[widx];
  int lr = lane & 15, kb = lane >> 4, hi4 = lane >> 4;
  long t0 = (long)c*QC;
  size_t bt0 = (size_t)b*SEQ + t0;
  int bh = b*NH + h;
  float Ac = -expf(A_log[h]);
  float Dk = Dskip[h];
  float dtv = dtT[(size_t)bh*SEQ + t0 + lane];
  float cum = dtv*Ac;
  #pragma unroll
  for (int off = 1; off < 64; off <<= 1){ float v = __shfl_up(cum, off, 64); if (lane >= off) cum += v; }
  cum_s[lane] = cum; dt_s[lane] = dtv;
  bf16x8 cf[4][2];
  #pragma unroll
  for (int ni = 0; ni < 4; ni++)
    #pragma unroll
    for (int kk = 0; kk < 2; kk++)
      cf[ni][kk] = *(const bf16x8*)&BCc[(bt0 + ni*16 + lr)*128 + 64 + kk*32 + kb*8];
  f32x4 g[4][4] = {};
  #pragma unroll
  for (int kk = 0; kk < 2; kk++){
    bf16x8 bfj[4];
    #pragma unroll
    for (int mi = 0; mi < 4; mi++) bfj[mi] = *(const bf16x8*)&BCc[(bt0 + mi*16 + lr)*128 + kk*32 + kb*8];
    #pragma unroll
    for (int mi = 0; mi < 4; mi++)
      #pragma unroll
      for (int ni = 0; ni < 4; ni++)
        g[mi][ni] = __builtin_amdgcn_mfma_f32_16x16x32_bf16(bfj[mi], cf[ni][kk], g[mi][ni], 0, 0, 0);
  }
  float cumi[4];
  #pragma unroll
  for (int ni = 0; ni < 4; ni++) cumi[ni] = cum_s[ni*16 + lr];
  #pragma unroll
  for (int mi = 0; mi < 4; mi++){
    #pragma unroll
    for (int r = 0; r < 4; r++){
      int j = mi*16 + hi4*4 + r;
      float cj = cum_s[j], dj = dt_s[j];
      #pragma unroll
      for (int ni = 0; ni < 4; ni++){
        int i = ni*16 + lr;
        float v = g[mi][ni][r];
        if (i > j)       v = v * __expf(cumi[ni] - cj) * dj;
        else if (i == j) v = v*dj + Dk;
        else             v = 0.f;
        g[mi][ni][r] = v;
      }
    }
  }
  #pragma unroll
  for (int mi = 0; mi < 4; mi++)
    #pragma unroll
    for (int ni = 0; ni < 4; ni++){
      int j0 = mi*16 + hi4*4;
      int i  = ni*16 + lr;
      bf16x4 v;
      #pragma unroll
      for (int r = 0; r < 4; r++) v[r] = (__bf16)g[mi][ni][r];
      *(bf16x4*)&Gs[i*LD + j0] = v;
    }
  const __bf16* Xp = xhT + ((size_t)bh*NCH + c)*4096;
  f32x4 y4[4][4] = {};
  #pragma unroll
  for (int kk = 0; kk < 2; kk++){
    bf16x8 af2[4], bf2[4];
    #pragma unroll
    for (int mi = 0; mi < 4; mi++) af2[mi] = *(const bf16x8*)&Xp[(mi*16+lr)*64 + kk*32 + kb*8];
    #pragma unroll
    for (int ni = 0; ni < 4; ni++) bf2[ni] = *(bf16x8*)&Gs[(ni*16+lr)*LD + kk*32 + kb*8];
    #pragma unroll
    for (int mi = 0; mi < 4; mi++)
      #pragma unroll
      for (int ni = 0; ni < 4; ni++)
        y4[mi][ni] = __builtin_amdgcn_mfma_f32_16x16x32_bf16(af2[mi], bf2[ni], y4[mi][ni], 0, 0, 0);
  }
  {
    const __bf16* Sp = Spre + ((size_t)bh*NCH + c)*4096;
    float ei[4];
    #pragma unroll
    for (int ni = 0; ni < 4; ni++) ei[ni] = __expf(cumi[ni]);
    #pragma unroll
    for (int kk = 0; kk < 2; kk++){
      bf16x8 as1[4];
      #pragma unroll
      for (int mi = 0; mi < 4; mi++) as1[mi] = *(const bf16x8*)&Sp[(mi*16+lr)*64 + kk*32 + kb*8];
      #pragma unroll
      for (int ni = 0; ni < 4; ni++){
        bf16x8 cs = scale8(cf[ni][kk], ei[ni]);
        #pragma unroll
        for (int mi = 0; mi < 4; mi++)
          y4[mi][ni] = __builtin_amdgcn_mfma_f32_16x16x32_bf16(as1[mi], cs, y4[mi][ni], 0, 0, 0);
      }
    }
  }
  #pragma unroll
  for (int mi = 0; mi < 4; mi++)
    #pragma unroll
    for (int ni = 0; ni < 4; ni++){
      int p0 = mi*16 + hi4*4;
      int i  = ni*16 + lr;
      bf16x4 v;
      #pragma unroll
      for (int r = 0; r < 4; r++) v[r] = (__bf16)y4[mi][ni][r];
      *(bf16x4*)&yout[(bt0 + i)*DINNER + h*HD + p0] = v;
    }
}

/* ---------------- gate (silu(z)) + RMSNorm(1024), in-place on y (bf16) ---------------- */
__global__ __launch_bounds__(256) void gate_rms(__bf16* __restrict__ y, const __bf16* __restrict__ zx,
                                                const float* __restrict__ nw){
  int row = blockIdx.x*4 + (threadIdx.x >> 6);
  int lane = threadIdx.x & 63;
  __bf16* yr = y + (size_t)row*DINNER + lane*16;
  const __bf16* zr = zx + (size_t)row*DPROJ + lane*16;
  bf16x8 y0 = *(const bf16x8*)yr, y1 = *(const bf16x8*)(yr+8);
  bf16x8 z0 = *(const bf16x8*)zr, z1 = *(const bf16x8*)(zr+8);
  float v[16]; float ss = 0.f;
  #pragma unroll
  for (int i = 0; i < 8; i++){ float z = (float)z0[i]; float tv = (float)y0[i]*siluf(z); v[i] = tv; ss += tv*tv; }
  #pragma unroll
  for (int i = 0; i < 8; i++){ float z = (float)z1[i]; float tv = (float)y1[i]*siluf(z); v[8+i] = tv; ss += tv*tv; }
  #pragma unroll
  for (int o = 32; o; o >>= 1) ss += __shfl_xor(ss, o, 64);
  float rs = rsqrtf(ss*(1.f/1024.f) + 1e-5f);
  const float* np = nw + lane*16;
  bf16x8 o0, o1;
  #pragma unroll
  for (int i = 0; i < 8; i++){ o0[i] = (__bf16)(v[i]*rs*np[i]); o1[i] = (__bf16)(v[8+i]*rs*np[8+i]); }
  *(bf16x8*)yr = o0; *(bf16x8*)(yr+8) = o1;
}

/* ---------------- classifier (bf16 h) ---------------- */
__global__ __launch_bounds__(256) void cls_kernel(const __bf16* __restrict__ h, const float* __restrict__ Wc,
                                                  const float* __restrict__ bc, float* __restrict__ out){
  int row = blockIdx.x*4 + (threadIdx.x >> 6);
  int lane = threadIdx.x & 63;
  const __bf16* hr = h + (size_t)row*DMODEL + lane*8;
  bf16x8 a = *(const bf16x8*)hr;
  float hv[8];
  #pragma unroll
  for (int i = 0; i < 8; i++) hv[i] = (float)a[i];
  const float* w0 = Wc + lane*8;
  const float* w1 = Wc + DMODEL + lane*8;
  float s0 = 0.f, s1 = 0.f;
  #pragma unroll
  for (int i = 0; i < 8; i++){ s0 += hv[i]*w0[i]; s1 += hv[i]*w1[i]; }
  #pragma unroll
  for (int o = 32; o; o >>= 1){ s0 += __shfl_xor(s0, o, 64); s1 += __shfl_xor(s1, o, 64); }
  if (lane == 0){ out[(size_t)row*2] = s0 + bc[0]; out[(size_t)row*2 + 1] = s1 + bc[1]; }
}

extern "C" void kernel_launch(void* const* d_in, const int* in_sizes, int n_in,
                              void* d_out, int out_size, void* d_ws, size_t ws_size,
                              hipStream_t stream){
  const float* x       = (const float*)d_in[0];
  const float* W1      = (const float*)d_in[1];
  const float* b1      = (const float*)d_in[2];
  const float* ln_w    = (const float*)d_in[3];
  const float* ln_b    = (const float*)d_in[4];
  const float* W_in    = (const float*)d_in[5];
  const float* conv_w  = (const float*)d_in[6];
  const float* conv_b  = (const float*)d_in[7];
  const float* dt_bias = (const float*)d_in[8];
  const float* A_log   = (const float*)d_in[9];
  const float* Dskip   = (const float*)d_in[10];
  const float* norm_w  = (const float*)d_in[11];
  const float* W_out   = (const float*)d_in[12];
  const float* Wc      = (const float*)d_in[13];
  const float* bc      = (const float*)d_in[14];
  float* out = (float*)d_out;
  char* ws = (char*)d_ws;

  size_t off = 0;
  auto alloc = [&](size_t bytes){ void* p = ws + off; off += (bytes + 255) & ~(size_t)255; return p; };
  char*   regionA = (char*) alloc((size_t)ROWS*DIN*2);          /* x_bf -> hnb -> Schunk */
  __bf16* W1b     = (__bf16*)alloc((size_t)DMODEL*DIN*2);
  __bf16* Winb    = (__bf16*)alloc(2L*NPAD*DMODEL*2);
  __bf16* Woutb   = (__bf16*)alloc(2L*DMODEL*DINNER*2);
  __bf16* h       = (__bf16*)alloc((size_t)ROWS*DMODEL*2);
  __bf16* zx      = (__bf16*)alloc((size_t)ROWS*DPROJ*2);
  __bf16* BCc     = (__bf16*)alloc((size_t)ROWS*128*2);
  float*  dtT     = (float*) alloc((size_t)ROWS*NH*4);
  __bf16* ybuf    = (__bf16*)alloc((size_t)ROWS*DINNER*2);
  __bf16* xhT     = (__bf16*)alloc((size_t)ROWS*DINNER*2);
  float*  Pbuf    = (float*) alloc(64L*NCH*4);
  if (off > ws_size) return;   /* diagnostic: zero output instead of OOB crash */

  __bf16* x_bf   = (__bf16*)regionA;
  __bf16* hnb    = (__bf16*)regionA;
  __bf16* Schunk = (__bf16*)regionA;

  cast_bf16_kernel<<<2048, 256, 0, stream>>>(x, x_bf, (long)ROWS*DIN/8);
  prep_weights<<<1024, 256, 0, stream>>>(W1, W_out, W_in, W1b, Woutb, Winb);

  /* h = gelu(x @ W1^T + b1) : 64x128, depth-3 prefetch */
  {
    dim3 g(ROWS/64, DMODEL/128);
    gemm_bt<__bf16,1,64,128,4><<<g, 256, 0, stream>>>(x_bf, W1b, h, b1, DIN, DMODEL);
  }

  for (int l = 0; l < 2; l++){
    ln_kernel<<<ROWS/4, 256, 0, stream>>>(h, ln_w + l*DMODEL, ln_b + l*DMODEL, hnb);
    {
      dim3 g(ROWS/128, NPAD/128);
      gemm_bt<__bf16,0,128,128,3><<<g, 256, 0, stream>>>(hnb, Winb + (size_t)l*NPAD*DMODEL, zx, nullptr, DMODEL, DPROJ);
    }
    convdt_kernel<<<(ROWS*144 + 255)/256, 256, 0, stream>>>(zx, conv_w + l*CONVDIM*4, conv_b + l*CONVDIM,
                                                            dt_bias + l*NH, BCc, dtT);
    {
      dim3 gs(NCH/2, NH, BATCH);
      ssd_state<<<gs, 128, 0, stream>>>(zx, BCc, dtT, A_log + l*NH,
                                        conv_w + l*CONVDIM*4, conv_b + l*CONVDIM, Schunk, Pbuf, xhT);
      ssd_comb<<<64*16, 64, 0, stream>>>(Schunk, Pbuf);
      dim3 gy(NCH/4, NH, BATCH);
      ssd_y<<<gy, 256, 0, stream>>>(BCc, dtT, A_log + l*NH, Dskip + l*NH, xhT, Schunk, ybuf);
    }
    gate_rms<<<ROWS/4, 256, 0, stream>>>(ybuf, zx, norm_w + l*DINNER);
    {
      dim3 g(ROWS/64, DMODEL/128);
      gemm_bt<__bf16,2,64,128,4><<<g, 256, 0, stream>>>(ybuf, Woutb + (size_t)l*DMODEL*DINNER, h, nullptr, DINNER, DMODEL);
    }
  }

  cls_kernel<<<ROWS/4, 256, 0, stream>>>(h, Wc, bc, out);
}

// Round 14
// 518.655 us; speedup vs baseline: 1.0104x; 1.0104x over previous
//
#include <hip/hip_runtime.h>
#include <hip/hip_bf16.h>
#include <math.h>

#define BATCH 4
#define SEQ 4096
#define ROWS 16384
#define DIN 1024
#define DMODEL 512
#define DINNER 1024
#define DSTATE 64
#define NH 16
#define HD 64
#define CONVDIM 1152              /* DINNER + 2*DSTATE */
#define DPROJ 2192                /* 2*DINNER + 2*DSTATE + NH */
#define NPAD 2304                 /* DPROJ padded to x128 */
#define QC 64                     /* SSD chunk length */
#define NCH 64                    /* SEQ/QC chunks per batch */
#define LD 72                     /* LDS tile stride (bf16 elems) */

typedef __attribute__((ext_vector_type(8))) __bf16 bf16x8;
typedef __attribute__((ext_vector_type(4))) __bf16 bf16x4;
typedef __attribute__((ext_vector_type(4))) float f32x4;

__device__ __forceinline__ float siluf(float x){ return x / (1.f + __expf(-x)); }
__device__ __forceinline__ float geluf(float x){ return 0.5f*x*(1.f + erff(x*0.70710678118654752440f)); }

__device__ __forceinline__ bf16x8 scale8(bf16x8 v, float s){
  bf16x8 r;
  #pragma unroll
  for (int e = 0; e < 8; e++) r[e] = (__bf16)((float)v[e]*s);
  return r;
}

/* async global->LDS, 16B per lane; lds base must be wave-uniform */
__device__ __forceinline__ void gl_lds16(const void* g, void* l){
  __builtin_amdgcn_global_load_lds((const __attribute__((address_space(1))) void*)g,
                                   (__attribute__((address_space(3))) void*)l, 16, 0, 0);
}

__device__ __forceinline__ bf16x8 cvt8(const float* sp){
  const float4* p = (const float4*)sp;
  float4 a = p[0], b = p[1];
  bf16x8 o;
  o[0]=(__bf16)a.x; o[1]=(__bf16)a.y; o[2]=(__bf16)a.z; o[3]=(__bf16)a.w;
  o[4]=(__bf16)b.x; o[5]=(__bf16)b.y; o[6]=(__bf16)b.z; o[7]=(__bf16)b.w;
  return o;
}

/* ---------------- prep: vectorized x cast ---------------- */
__global__ void cast_bf16_kernel(const float* __restrict__ src, __bf16* __restrict__ dst, long n8){
  long i = (long)blockIdx.x*blockDim.x + threadIdx.x;
  long stride = (long)gridDim.x*blockDim.x;
  for (; i < n8; i += stride) *(bf16x8*)(dst + i*8) = cvt8(src + i*8);
}

/* ---------------- merged weight prep: W1, W_out, W_in(padded) ---------------- */
#define W1G   (DMODEL*DIN/8)            /* 65536  */
#define WOG   (2*DMODEL*DINNER/8)       /* 131072 */
#define WIG   (2L*NPAD*(DMODEL/8))      /* 294912 */
__global__ void prep_weights(const float* __restrict__ W1, const float* __restrict__ W_out,
                             const float* __restrict__ W_in, __bf16* __restrict__ W1b,
                             __bf16* __restrict__ Woutb, __bf16* __restrict__ Winb){
  long total = W1G + WOG + WIG;
  long i = (long)blockIdx.x*blockDim.x + threadIdx.x;
  long stride = (long)gridDim.x*blockDim.x;
  for (; i < total; i += stride){
    if (i < W1G){
      *(bf16x8*)(W1b + i*8) = cvt8(W1 + i*8);
    } else if (i < W1G + WOG){
      long j = i - W1G;
      *(bf16x8*)(Woutb + j*8) = cvt8(W_out + j*8);
    } else {
      long j = i - W1G - WOG;
      int k8 = (int)(j % (DMODEL/8));
      int n  = (int)((j / (DMODEL/8)) % NPAD);
      int l  = (int)(j / ((long)(DMODEL/8)*NPAD));
      bf16x8 o;
      if (n < DPROJ){
        o = cvt8(W_in + ((long)l*DPROJ + n)*DMODEL + k8*8);
      } else {
        #pragma unroll
        for (int e = 0; e < 8; e++) o[e] = (__bf16)0.f;
      }
      *(bf16x8*)(Winb + ((long)l*NPAD + n)*DMODEL + k8*8) = o;
    }
  }
}

/* ---------------- GEMM (4-wave, BMxBN, BK=32): triple-buffer depth-2 + XCD swizzle ----------------
   Grid is launched 1D (nbm*nbn blocks, nbm*nbn % 8 == 0); bijective XCD remap groups a
   contiguous chunk of (bm,bn) space per XCD for L2 locality (T1; guide m204 form). */
template<typename OutT, int EPI, int BM, int BN>
__global__ __launch_bounds__(256) void gemm_bt(const __bf16* __restrict__ A, const __bf16* __restrict__ Bm,
                                               OutT* __restrict__ C, const float* __restrict__ bias,
                                               int K, int Nc, int nbm){
  constexpr int MI = BM/32, NI = BN/32;
  constexpr int CHA = BM/64;
  constexpr int CHT = (BM+BN)/64;
  __shared__ __align__(16) __bf16 As[3][BM*32];
  __shared__ __align__(16) __bf16 Bs[3][BN*32];
  int nwg = gridDim.x;
  int cpx = nwg >> 3;                       /* nwg % 8 == 0 guaranteed by launch */
  int lin = blockIdx.x;
  int swz = (lin & 7)*cpx + (lin >> 3);
  int bm = swz % nbm, bn = swz / nbm;
  int tid = threadIdx.x;
  int lane = tid & 63, wid = tid >> 6;
  int wm = (wid >> 1)*(BM/2), wn = (wid & 1)*(BN/2);
  int lr = lane & 15, kb = lane >> 4;
  f32x4 acc[MI][NI] = {};
  const char* Ab = (const char*)A + (size_t)bm*BM*(size_t)(K*2);
  const char* Bb = (const char*)Bm + (size_t)bn*BN*(size_t)(K*2);
  int nkk = K >> 5;

  auto STAGE = [&](int kk, int buf){
    #pragma unroll
    for (int it = 0; it < CHT; it++){
      int cbase = it*4096 + wid*1024;
      int off = cbase + lane*16;
      int row = off >> 6, cb = off & 63;
      if (it < CHA) gl_lds16(Ab + (size_t)row*(K*2) + kk*64 + cb, (char*)(&As[buf][0]) + cbase);
      else          gl_lds16(Bb + (size_t)(row - BM)*(K*2) + kk*64 + cb, (char*)(&Bs[buf][0]) + (cbase - BM*64));
    }
  };

  STAGE(0, 0);
  if (nkk > 1) STAGE(1, 1);
  for (int kk = 0; kk < nkk; kk++){
    int cur = kk % 3;
    if (kk + 2 < nkk){
      STAGE(kk + 2, (kk + 2) % 3);
      asm volatile("s_waitcnt vmcnt(%0)" :: "n"(2*CHT) : "memory");
    } else if (kk + 1 < nkk){
      asm volatile("s_waitcnt vmcnt(%0)" :: "n"(CHT) : "memory");
    } else {
      asm volatile("s_waitcnt vmcnt(0)" ::: "memory");
    }
    __builtin_amdgcn_sched_barrier(0);
    __builtin_amdgcn_s_barrier();
    __builtin_amdgcn_sched_barrier(0);
    const __bf16* Asb = &As[cur][0];
    const __bf16* Bsb = &Bs[cur][0];
    bf16x8 af[MI], bfr[NI];
    #pragma unroll
    for (int mi = 0; mi < MI; mi++) af[mi] = *(const bf16x8*)(Asb + (wm + mi*16 + lr)*32 + kb*8);
    #pragma unroll
    for (int ni = 0; ni < NI; ni++) bfr[ni] = *(const bf16x8*)(Bsb + (wn + ni*16 + lr)*32 + kb*8);
    #pragma unroll
    for (int mi = 0; mi < MI; mi++)
      #pragma unroll
      for (int ni = 0; ni < NI; ni++)
        acc[mi][ni] = __builtin_amdgcn_mfma_f32_16x16x32_bf16(af[mi], bfr[ni], acc[mi][ni], 0, 0, 0);
    __builtin_amdgcn_s_barrier();
    __builtin_amdgcn_sched_barrier(0);
  }
  #pragma unroll
  for (int mi = 0; mi < MI; mi++){
    #pragma unroll
    for (int ni = 0; ni < NI; ni++){
      int r0 = bm*BM + wm + mi*16 + (lane >> 4)*4;
      int c  = bn*BN + wn + ni*16 + lr;
      if (c < Nc){
        OutT* Cp = C + (size_t)r0*Nc + c;
        #pragma unroll
        for (int j = 0; j < 4; j++){
          float v = acc[mi][ni][j];
          if (EPI == 1){ float u = v + bias[c]; v = geluf(u); }
          if (EPI == 2){ v += (float)Cp[(size_t)j*Nc]; }
          Cp[(size_t)j*Nc] = (OutT)v;
        }
      }
    }
  }
}

/* ---------------- LayerNorm row(512) bf16 -> bf16 ---------------- */
__global__ __launch_bounds__(256) void ln_kernel(const __bf16* __restrict__ h, const float* __restrict__ w,
                                                 const float* __restrict__ b, __bf16* __restrict__ out){
  int row = blockIdx.x*4 + (threadIdx.x >> 6);
  int lane = threadIdx.x & 63;
  const __bf16* hr = h + (size_t)row*DMODEL + lane*8;
  bf16x8 a = *(const bf16x8*)hr;
  float v[8];
  #pragma unroll
  for (int i = 0; i < 8; i++) v[i] = (float)a[i];
  float s = 0.f;
  #pragma unroll
  for (int i = 0; i < 8; i++) s += v[i];
  #pragma unroll
  for (int o = 32; o; o >>= 1) s += __shfl_xor(s, o, 64);
  float mu = s*(1.f/512.f);
  float q = 0.f;
  #pragma unroll
  for (int i = 0; i < 8; i++){ float d = v[i]-mu; q += d*d; }
  #pragma unroll
  for (int o = 32; o; o >>= 1) q += __shfl_xor(q, o, 64);
  float rs = rsqrtf(q*(1.f/512.f) + 1e-5f);
  const float* wp = w + lane*8; const float* bp = b + lane*8;
  bf16x8 o8;
  #pragma unroll
  for (int i = 0; i < 8; i++) o8[i] = (__bf16)((v[i]-mu)*rs*wp[i] + bp[i]);
  *(bf16x8*)(out + (size_t)row*DMODEL + lane*8) = o8;
}

/* ---------------- merged conv+SiLU (B/C channels) and dt=softplus ---------------- */
__global__ __launch_bounds__(256) void convdt_kernel(const __bf16* __restrict__ zx, const float* __restrict__ cw,
                                                     const float* __restrict__ cb, const float* __restrict__ dt_bias,
                                                     __bf16* __restrict__ BCc, float* __restrict__ dtT){
  long idx = (long)blockIdx.x*256 + threadIdx.x;   /* ROWS*144 */
  long bt = idx / 144;
  int j = (int)(idx - bt*144);
  if (bt >= ROWS) return;
  int t = (int)(bt & (SEQ-1));
  int b = (int)(bt >> 12);
  if (j < 128){
    int ch = DINNER + j;
    const __bf16* src = zx + (size_t)bt*DPROJ + 2048 + j;
    float acc = cb[ch] + (float)src[0]*cw[ch*4+3];
    if (t >= 1) acc += (float)src[-1L*DPROJ]*cw[ch*4+2];
    if (t >= 2) acc += (float)src[-2L*DPROJ]*cw[ch*4+1];
    if (t >= 3) acc += (float)src[-3L*DPROJ]*cw[ch*4+0];
    BCc[(size_t)bt*128 + j] = (__bf16)siluf(acc);
  } else {
    int hh = j - 128;
    float v = (float)zx[(size_t)bt*DPROJ + (DPROJ-NH) + hh] + dt_bias[hh];
    float sp = (v > 20.f) ? v : log1pf(__expf(v));
    dtT[((size_t)b*NH + hh)*SEQ + t] = sp;
  }
}

/* ================= SSD kernel A — per-chunk state via MFMA (2 waves/block) ================= */
__global__ __launch_bounds__(128) void ssd_state(const __bf16* __restrict__ zx, const __bf16* __restrict__ BCc,
                                                 const float* __restrict__ dtT, const float* __restrict__ A_log,
                                                 const float* __restrict__ cw, const float* __restrict__ cb,
                                                 __bf16* __restrict__ Schunk, float* __restrict__ Pbuf,
                                                 __bf16* __restrict__ xhT){
  __shared__ __align__(16) __bf16 Bt_all[2][64*LD];
  __shared__ __align__(16) __bf16 Xt_all[2][64*LD];
  int widx = threadIdx.x >> 6, lane = threadIdx.x & 63;
  int c = blockIdx.x*2 + widx, h = blockIdx.y, b = blockIdx.z;
  __bf16* Bt = Bt_all[widx];
  __bf16* Xt = Xt_all[widx];
  int lr = lane & 15, kb = lane >> 4, hi4 = lane >> 4;
  long t0 = (long)c*QC;
  size_t bt0 = (size_t)b*SEQ + t0;
  int bh = b*NH + h;
  float Ac = -expf(A_log[h]);
  float dtv = dtT[(size_t)bh*SEQ + t0 + lane];
  float cum = dtv*Ac;
  #pragma unroll
  for (int off = 1; off < 64; off <<= 1){ float v = __shfl_up(cum, off, 64); if (lane >= off) cum += v; }
  float cumQ = __shfl(cum, 63, 64);
  float w = __expf(cumQ - cum) * dtv;
  {
    const __bf16* bp = BCc + bt0*128 + lane;
    for (int tb = 0; tb < 8; tb++){
      bf16x8 buf;
      #pragma unroll
      for (int u = 0; u < 8; u++){
        int t = tb*8 + u;
        float bv = (float)bp[(size_t)t*128];
        buf[u] = (__bf16)(bv * __shfl(w, t, 64));
      }
      *(bf16x8*)&Bt[lane*LD + tb*8] = buf;
    }
  }
  {
    int ch = h*HD + lane;
    float w0 = cw[ch*4], w1 = cw[ch*4+1], w2 = cw[ch*4+2], w3 = cw[ch*4+3], cbv = cb[ch];
    const __bf16* xp = zx + bt0*DPROJ + (DINNER + ch);
    float x1 = (t0 >= 1) ? (float)xp[-1L*DPROJ] : 0.f;
    float x2 = (t0 >= 2) ? (float)xp[-2L*DPROJ] : 0.f;
    float x3 = (t0 >= 3) ? (float)xp[-3L*DPROJ] : 0.f;
    __bf16* xo = xhT + ((size_t)bh*NCH + c)*4096 + lane*64;
    for (int tb = 0; tb < 8; tb++){
      bf16x8 buf;
      #pragma unroll
      for (int u = 0; u < 8; u++){
        int t = tb*8 + u;
        float x0 = (float)xp[(size_t)t*DPROJ];
        float xv = siluf(cbv + w3*x0 + w2*x1 + w1*x2 + w0*x3);
        x3 = x2; x2 = x1; x1 = x0;
        buf[u] = (__bf16)xv;
      }
      *(bf16x8*)&Xt[lane*LD + tb*8] = buf;
      *(bf16x8*)(xo + tb*8) = buf;
    }
  }
  f32x4 acc[4][4] = {};
  #pragma unroll
  for (int kk = 0; kk < 2; kk++){
    bf16x8 af[4], bfr[4];
    #pragma unroll
    for (int mi = 0; mi < 4; mi++) af[mi]  = *(bf16x8*)&Bt[(mi*16+lr)*LD + kk*32 + kb*8];
    #pragma unroll
    for (int ni = 0; ni < 4; ni++) bfr[ni] = *(bf16x8*)&Xt[(ni*16+lr)*LD + kk*32 + kb*8];
    #pragma unroll
    for (int mi = 0; mi < 4; mi++)
      #pragma unroll
      for (int ni = 0; ni < 4; ni++)
        acc[mi][ni] = __builtin_amdgcn_mfma_f32_16x16x32_bf16(af[mi], bfr[ni], acc[mi][ni], 0, 0, 0);
  }
  __bf16* Sp = Schunk + ((size_t)bh*NCH + c)*4096;
  #pragma unroll
  for (int mi = 0; mi < 4; mi++)
    #pragma unroll
    for (int ni = 0; ni < 4; ni++){
      int n0 = mi*16 + hi4*4;
      int p  = ni*16 + lr;
      bf16x4 v;
      #pragma unroll
      for (int r = 0; r < 4; r++) v[r] = (__bf16)acc[mi][ni][r];
      *(bf16x4*)&Sp[p*64 + n0] = v;
    }
  if (lane == 0) Pbuf[bh*NCH + c] = __expf(cumQ);
}

/* ========== in-place chunk-state -> prefix-state ========== */
__global__ __launch_bounds__(64) void ssd_comb(__bf16* __restrict__ Schunk, const float* __restrict__ Pbuf){
  int bh = blockIdx.x >> 4;
  int eb = blockIdx.x & 15;
  int e = eb*256 + threadIdx.x*4;
  __bf16* base = Schunk + (size_t)bh*NCH*4096 + e;
  float T0 = 0.f, T1 = 0.f, T2 = 0.f, T3 = 0.f;
  for (int c = 0; c < NCH; c++){
    float P = Pbuf[bh*NCH + c];
    bf16x4* p = (bf16x4*)(base + (size_t)c*4096);
    bf16x4 s = *p;
    bf16x4 o; o[0] = (__bf16)T0; o[1] = (__bf16)T1; o[2] = (__bf16)T2; o[3] = (__bf16)T3;
    *p = o;
    T0 = T0*P + (float)s[0]; T1 = T1*P + (float)s[1];
    T2 = T2*P + (float)s[2]; T3 = T3*P + (float)s[3];
  }
}

/* ================= SSD kernel B — outputs via MFMA (4 waves/block, per-wave LDS) ================= */
__global__ __launch_bounds__(256) void ssd_y(const __bf16* __restrict__ BCc, const float* __restrict__ dtT,
                                             const float* __restrict__ A_log, const float* __restrict__ Dskip,
                                             const __bf16* __restrict__ xhT, const __bf16* __restrict__ Spre,
                                             __bf16* __restrict__ yout){
  __shared__ __align__(16) __bf16 Gs_all[4][64*LD];
  __shared__ float cum_all[4][64], dt_all[4][64];
  int widx = threadIdx.x >> 6, lane = threadIdx.x & 63;
  int c = blockIdx.x*4 + widx, h = blockIdx.y, b = blockIdx.z;
  __bf16* Gs = Gs_all[widx];
  float* cum_s = cum_all[widx];
  float* dt_s = dt_all[widx];
  int lr = lane & 15, kb = lane >> 4, hi4 = lane >> 4;
  long t0 = (long)c*QC;
  size_t bt0 = (size_t)b*SEQ + t0;
  int bh = b*NH + h;
  float Ac = -expf(A_log[h]);
  float Dk = Dskip[h];
  float dtv = dtT[(size_t)bh*SEQ + t0 + lane];
  float cum = dtv*Ac;
  #pragma unroll
  for (int off = 1; off < 64; off <<= 1){ float v = __shfl_up(cum, off, 64); if (lane >= off) cum += v; }
  cum_s[lane] = cum; dt_s[lane] = dtv;
  bf16x8 cf[4][2];
  #pragma unroll
  for (int ni = 0; ni < 4; ni++)
    #pragma unroll
    for (int kk = 0; kk < 2; kk++)
      cf[ni][kk] = *(const bf16x8*)&BCc[(bt0 + ni*16 + lr)*128 + 64 + kk*32 + kb*8];
  f32x4 g[4][4] = {};
  #pragma unroll
  for (int kk = 0; kk < 2; kk++){
    bf16x8 bfj[4];
    #pragma unroll
    for (int mi = 0; mi < 4; mi++) bfj[mi] = *(const bf16x8*)&BCc[(bt0 + mi*16 + lr)*128 + kk*32 + kb*8];
    #pragma unroll
    for (int mi = 0; mi < 4; mi++)
      #pragma unroll
      for (int ni = 0; ni < 4; ni++)
        g[mi][ni] = __builtin_amdgcn_mfma_f32_16x16x32_bf16(bfj[mi], cf[ni][kk], g[mi][ni], 0, 0, 0);
  }
  float cumi[4];
  #pragma unroll
  for (int ni = 0; ni < 4; ni++) cumi[ni] = cum_s[ni*16 + lr];
  #pragma unroll
  for (int mi = 0; mi < 4; mi++){
    #pragma unroll
    for (int r = 0; r < 4; r++){
      int j = mi*16 + hi4*4 + r;
      float cj = cum_s[j], dj = dt_s[j];
      #pragma unroll
      for (int ni = 0; ni < 4; ni++){
        int i = ni*16 + lr;
        float v = g[mi][ni][r];
        if (i > j)       v = v * __expf(cumi[ni] - cj) * dj;
        else if (i == j) v = v*dj + Dk;
        else             v = 0.f;
        g[mi][ni][r] = v;
      }
    }
  }
  #pragma unroll
  for (int mi = 0; mi < 4; mi++)
    #pragma unroll
    for (int ni = 0; ni < 4; ni++){
      int j0 = mi*16 + hi4*4;
      int i  = ni*16 + lr;
      bf16x4 v;
      #pragma unroll
      for (int r = 0; r < 4; r++) v[r] = (__bf16)g[mi][ni][r];
      *(bf16x4*)&Gs[i*LD + j0] = v;
    }
  const __bf16* Xp = xhT + ((size_t)bh*NCH + c)*4096;
  f32x4 y4[4][4] = {};
  #pragma unroll
  for (int kk = 0; kk < 2; kk++){
    bf16x8 af2[4], bf2[4];
    #pragma unroll
    for (int mi = 0; mi < 4; mi++) af2[mi] = *(const bf16x8*)&Xp[(mi*16+lr)*64 + kk*32 + kb*8];
    #pragma unroll
    for (int ni = 0; ni < 4; ni++) bf2[ni] = *(bf16x8*)&Gs[(ni*16+lr)*LD + kk*32 + kb*8];
    #pragma unroll
    for (int mi = 0; mi < 4; mi++)
      #pragma unroll
      for (int ni = 0; ni < 4; ni++)
        y4[mi][ni] = __builtin_amdgcn_mfma_f32_16x16x32_bf16(af2[mi], bf2[ni], y4[mi][ni], 0, 0, 0);
  }
  {
    const __bf16* Sp = Spre + ((size_t)bh*NCH + c)*4096;
    float ei[4];
    #pragma unroll
    for (int ni = 0; ni < 4; ni++) ei[ni] = __expf(cumi[ni]);
    #pragma unroll
    for (int kk = 0; kk < 2; kk++){
      bf16x8 as1[4];
      #pragma unroll
      for (int mi = 0; mi < 4; mi++) as1[mi] = *(const bf16x8*)&Sp[(mi*16+lr)*64 + kk*32 + kb*8];
      #pragma unroll
      for (int ni = 0; ni < 4; ni++){
        bf16x8 cs = scale8(cf[ni][kk], ei[ni]);
        #pragma unroll
        for (int mi = 0; mi < 4; mi++)
          y4[mi][ni] = __builtin_amdgcn_mfma_f32_16x16x32_bf16(as1[mi], cs, y4[mi][ni], 0, 0, 0);
      }
    }
  }
  #pragma unroll
  for (int mi = 0; mi < 4; mi++)
    #pragma unroll
    for (int ni = 0; ni < 4; ni++){
      int p0 = mi*16 + hi4*4;
      int i  = ni*16 + lr;
      bf16x4 v;
      #pragma unroll
      for (int r = 0; r < 4; r++) v[r] = (__bf16)y4[mi][ni][r];
      *(bf16x4*)&yout[(bt0 + i)*DINNER + h*HD + p0] = v;
    }
}

/* ---------------- gate (silu(z)) + RMSNorm(1024), in-place on y (bf16) ---------------- */
__global__ __launch_bounds__(256) void gate_rms(__bf16* __restrict__ y, const __bf16* __restrict__ zx,
                                                const float* __restrict__ nw){
  int row = blockIdx.x*4 + (threadIdx.x >> 6);
  int lane = threadIdx.x & 63;
  __bf16* yr = y + (size_t)row*DINNER + lane*16;
  const __bf16* zr = zx + (size_t)row*DPROJ + lane*16;
  bf16x8 y0 = *(const bf16x8*)yr, y1 = *(const bf16x8*)(yr+8);
  bf16x8 z0 = *(const bf16x8*)zr, z1 = *(const bf16x8*)(zr+8);
  float v[16]; float ss = 0.f;
  #pragma unroll
  for (int i = 0; i < 8; i++){ float z = (float)z0[i]; float tv = (float)y0[i]*siluf(z); v[i] = tv; ss += tv*tv; }
  #pragma unroll
  for (int i = 0; i < 8; i++){ float z = (float)z1[i]; float tv = (float)y1[i]*siluf(z); v[8+i] = tv; ss += tv*tv; }
  #pragma unroll
  for (int o = 32; o; o >>= 1) ss += __shfl_xor(ss, o, 64);
  float rs = rsqrtf(ss*(1.f/1024.f) + 1e-5f);
  const float* np = nw + lane*16;
  bf16x8 o0, o1;
  #pragma unroll
  for (int i = 0; i < 8; i++){ o0[i] = (__bf16)(v[i]*rs*np[i]); o1[i] = (__bf16)(v[8+i]*rs*np[8+i]); }
  *(bf16x8*)yr = o0; *(bf16x8*)(yr+8) = o1;
}

/* ---------------- classifier (bf16 h) ---------------- */
__global__ __launch_bounds__(256) void cls_kernel(const __bf16* __restrict__ h, const float* __restrict__ Wc,
                                                  const float* __restrict__ bc, float* __restrict__ out){
  int row = blockIdx.x*4 + (threadIdx.x >> 6);
  int lane = threadIdx.x & 63;
  const __bf16* hr = h + (size_t)row*DMODEL + lane*8;
  bf16x8 a = *(const bf16x8*)hr;
  float hv[8];
  #pragma unroll
  for (int i = 0; i < 8; i++) hv[i] = (float)a[i];
  const float* w0 = Wc + lane*8;
  const float* w1 = Wc + DMODEL + lane*8;
  float s0 = 0.f, s1 = 0.f;
  #pragma unroll
  for (int i = 0; i < 8; i++){ s0 += hv[i]*w0[i]; s1 += hv[i]*w1[i]; }
  #pragma unroll
  for (int o = 32; o; o >>= 1){ s0 += __shfl_xor(s0, o, 64); s1 += __shfl_xor(s1, o, 64); }
  if (lane == 0){ out[(size_t)row*2] = s0 + bc[0]; out[(size_t)row*2 + 1] = s1 + bc[1]; }
}

extern "C" void kernel_launch(void* const* d_in, const int* in_sizes, int n_in,
                              void* d_out, int out_size, void* d_ws, size_t ws_size,
                              hipStream_t stream){
  const float* x       = (const float*)d_in[0];
  const float* W1      = (const float*)d_in[1];
  const float* b1      = (const float*)d_in[2];
  const float* ln_w    = (const float*)d_in[3];
  const float* ln_b    = (const float*)d_in[4];
  const float* W_in    = (const float*)d_in[5];
  const float* conv_w  = (const float*)d_in[6];
  const float* conv_b  = (const float*)d_in[7];
  const float* dt_bias = (const float*)d_in[8];
  const float* A_log   = (const float*)d_in[9];
  const float* Dskip   = (const float*)d_in[10];
  const float* norm_w  = (const float*)d_in[11];
  const float* W_out   = (const float*)d_in[12];
  const float* Wc      = (const float*)d_in[13];
  const float* bc      = (const float*)d_in[14];
  float* out = (float*)d_out;
  char* ws = (char*)d_ws;

  size_t off = 0;
  auto alloc = [&](size_t bytes){ void* p = ws + off; off += (bytes + 255) & ~(size_t)255; return p; };
  char*   regionA = (char*) alloc((size_t)ROWS*DIN*2);          /* x_bf -> hnb -> Schunk */
  __bf16* W1b     = (__bf16*)alloc((size_t)DMODEL*DIN*2);
  __bf16* Winb    = (__bf16*)alloc(2L*NPAD*DMODEL*2);
  __bf16* Woutb   = (__bf16*)alloc(2L*DMODEL*DINNER*2);
  __bf16* h       = (__bf16*)alloc((size_t)ROWS*DMODEL*2);
  __bf16* zx      = (__bf16*)alloc((size_t)ROWS*DPROJ*2);
  __bf16* BCc     = (__bf16*)alloc((size_t)ROWS*128*2);
  float*  dtT     = (float*) alloc((size_t)ROWS*NH*4);
  __bf16* ybuf    = (__bf16*)alloc((size_t)ROWS*DINNER*2);
  __bf16* xhT     = (__bf16*)alloc((size_t)ROWS*DINNER*2);
  float*  Pbuf    = (float*) alloc(64L*NCH*4);
  if (off > ws_size) return;   /* diagnostic: zero output instead of OOB crash */

  __bf16* x_bf   = (__bf16*)regionA;
  __bf16* hnb    = (__bf16*)regionA;
  __bf16* Schunk = (__bf16*)regionA;

  cast_bf16_kernel<<<2048, 256, 0, stream>>>(x, x_bf, (long)ROWS*DIN/8);
  prep_weights<<<1024, 256, 0, stream>>>(W1, W_out, W_in, W1b, Woutb, Winb);

  /* h = gelu(x @ W1^T + b1) : 64x128 (r8/r12 config) + XCD swizzle; 1024 blocks */
  gemm_bt<__bf16,1,64,128><<<(ROWS/64)*(DMODEL/128), 256, 0, stream>>>(x_bf, W1b, h, b1, DIN, DMODEL, ROWS/64);

  for (int l = 0; l < 2; l++){
    ln_kernel<<<ROWS/4, 256, 0, stream>>>(h, ln_w + l*DMODEL, ln_b + l*DMODEL, hnb);
    /* W_in GEMM : 128x128 + XCD swizzle; 2304 blocks (%8==0) */
    gemm_bt<__bf16,0,128,128><<<(ROWS/128)*(NPAD/128), 256, 0, stream>>>(hnb, Winb + (size_t)l*NPAD*DMODEL,
                                                                          zx, nullptr, DMODEL, DPROJ, ROWS/128);
    convdt_kernel<<<(ROWS*144 + 255)/256, 256, 0, stream>>>(zx, conv_w + l*CONVDIM*4, conv_b + l*CONVDIM,
                                                            dt_bias + l*NH, BCc, dtT);
    {
      dim3 gs(NCH/2, NH, BATCH);
      ssd_state<<<gs, 128, 0, stream>>>(zx, BCc, dtT, A_log + l*NH,
                                        conv_w + l*CONVDIM*4, conv_b + l*CONVDIM, Schunk, Pbuf, xhT);
      ssd_comb<<<64*16, 64, 0, stream>>>(Schunk, Pbuf);
      dim3 gy(NCH/4, NH, BATCH);
      ssd_y<<<gy, 256, 0, stream>>>(BCc, dtT, A_log + l*NH, Dskip + l*NH, xhT, Schunk, ybuf);
    }
    gate_rms<<<ROWS/4, 256, 0, stream>>>(ybuf, zx, norm_w + l*DINNER);
    gemm_bt<__bf16,2,64,128><<<(ROWS/64)*(DMODEL/128), 256, 0, stream>>>(ybuf, Woutb + (size_t)l*DMODEL*DINNER,
                                                                          h, nullptr, DINNER, DMODEL, ROWS/64);
  }

  cls_kernel<<<ROWS/4, 256, 0, stream>>>(h, Wc, bc, out);
}

// Round 15
// 470.361 us; speedup vs baseline: 1.1142x; 1.1027x over previous
//
#include <hip/hip_runtime.h>
#include <hip/hip_bf16.h>
#include <math.h>

#define BATCH 4
#define SEQ 4096
#define ROWS 16384
#define DIN 1024
#define DMODEL 512
#define DINNER 1024
#define DSTATE 64
#define NH 16
#define HD 64
#define CONVDIM 1152              /* DINNER + 2*DSTATE */
#define DPROJ 2192                /* 2*DINNER + 2*DSTATE + NH */
#define NPAD 2304                 /* DPROJ padded to x128 */
#define QC 64                     /* SSD chunk length */
#define NCH 64                    /* SEQ/QC chunks per batch */
#define LD 72                     /* LDS tile stride (bf16 elems) */

typedef __attribute__((ext_vector_type(8))) __bf16 bf16x8;
typedef __attribute__((ext_vector_type(4))) __bf16 bf16x4;
typedef __attribute__((ext_vector_type(4))) float f32x4;

__device__ __forceinline__ float siluf(float x){ return x / (1.f + __expf(-x)); }
__device__ __forceinline__ float geluf(float x){ return 0.5f*x*(1.f + erff(x*0.70710678118654752440f)); }

__device__ __forceinline__ bf16x8 scale8(bf16x8 v, float s){
  bf16x8 r;
  #pragma unroll
  for (int e = 0; e < 8; e++) r[e] = (__bf16)((float)v[e]*s);
  return r;
}

/* async global->LDS, 16B per lane; lds base must be wave-uniform */
__device__ __forceinline__ void gl_lds16(const void* g, void* l){
  __builtin_amdgcn_global_load_lds((const __attribute__((address_space(1))) void*)g,
                                   (__attribute__((address_space(3))) void*)l, 16, 0, 0);
}

__device__ __forceinline__ bf16x8 cvt8(const float* sp){
  const float4* p = (const float4*)sp;
  float4 a = p[0], b = p[1];
  bf16x8 o;
  o[0]=(__bf16)a.x; o[1]=(__bf16)a.y; o[2]=(__bf16)a.z; o[3]=(__bf16)a.w;
  o[4]=(__bf16)b.x; o[5]=(__bf16)b.y; o[6]=(__bf16)b.z; o[7]=(__bf16)b.w;
  return o;
}

/* ---------------- prep: vectorized x cast ---------------- */
__global__ void cast_bf16_kernel(const float* __restrict__ src, __bf16* __restrict__ dst, long n8){
  long i = (long)blockIdx.x*blockDim.x + threadIdx.x;
  long stride = (long)gridDim.x*blockDim.x;
  for (; i < n8; i += stride) *(bf16x8*)(dst + i*8) = cvt8(src + i*8);
}

/* ---------------- merged weight prep: W1, W_out, W_in(padded) ---------------- */
#define W1G   (DMODEL*DIN/8)            /* 65536  */
#define WOG   (2*DMODEL*DINNER/8)       /* 131072 */
#define WIG   (2L*NPAD*(DMODEL/8))      /* 294912 */
__global__ void prep_weights(const float* __restrict__ W1, const float* __restrict__ W_out,
                             const float* __restrict__ W_in, __bf16* __restrict__ W1b,
                             __bf16* __restrict__ Woutb, __bf16* __restrict__ Winb){
  long total = W1G + WOG + WIG;
  long i = (long)blockIdx.x*blockDim.x + threadIdx.x;
  long stride = (long)gridDim.x*blockDim.x;
  for (; i < total; i += stride){
    if (i < W1G){
      *(bf16x8*)(W1b + i*8) = cvt8(W1 + i*8);
    } else if (i < W1G + WOG){
      long j = i - W1G;
      *(bf16x8*)(Woutb + j*8) = cvt8(W_out + j*8);
    } else {
      long j = i - W1G - WOG;
      int k8 = (int)(j % (DMODEL/8));
      int n  = (int)((j / (DMODEL/8)) % NPAD);
      int l  = (int)(j / ((long)(DMODEL/8)*NPAD));
      bf16x8 o;
      if (n < DPROJ){
        o = cvt8(W_in + ((long)l*DPROJ + n)*DMODEL + k8*8);
      } else {
        #pragma unroll
        for (int e = 0; e < 8; e++) o[e] = (__bf16)0.f;
      }
      *(bf16x8*)(Winb + ((long)l*NPAD + n)*DMODEL + k8*8) = o;
    }
  }
}

/* ---------------- GEMM (4-wave, BMxBN, BK=32): triple-buffer depth-2 (r12 measured-best). ---------------- */
template<typename OutT, int EPI, int BM, int BN>
__global__ __launch_bounds__(256) void gemm_bt(const __bf16* __restrict__ A, const __bf16* __restrict__ Bm,
                                               OutT* __restrict__ C, const float* __restrict__ bias,
                                               int K, int Nc){
  constexpr int MI = BM/32, NI = BN/32;
  constexpr int CHA = BM/64;
  constexpr int CHT = (BM+BN)/64;
  __shared__ __align__(16) __bf16 As[3][BM*32];
  __shared__ __align__(16) __bf16 Bs[3][BN*32];
  int bm = blockIdx.x, bn = blockIdx.y;
  int tid = threadIdx.x;
  int lane = tid & 63, wid = tid >> 6;
  int wm = (wid >> 1)*(BM/2), wn = (wid & 1)*(BN/2);
  int lr = lane & 15, kb = lane >> 4;
  f32x4 acc[MI][NI] = {};
  const char* Ab = (const char*)A + (size_t)bm*BM*(size_t)(K*2);
  const char* Bb = (const char*)Bm + (size_t)bn*BN*(size_t)(K*2);
  int nkk = K >> 5;

  auto STAGE = [&](int kk, int buf){
    #pragma unroll
    for (int it = 0; it < CHT; it++){
      int cbase = it*4096 + wid*1024;
      int off = cbase + lane*16;
      int row = off >> 6, cb = off & 63;
      if (it < CHA) gl_lds16(Ab + (size_t)row*(K*2) + kk*64 + cb, (char*)(&As[buf][0]) + cbase);
      else          gl_lds16(Bb + (size_t)(row - BM)*(K*2) + kk*64 + cb, (char*)(&Bs[buf][0]) + (cbase - BM*64));
    }
  };

  STAGE(0, 0);
  if (nkk > 1) STAGE(1, 1);
  for (int kk = 0; kk < nkk; kk++){
    int cur = kk % 3;
    if (kk + 2 < nkk){
      STAGE(kk + 2, (kk + 2) % 3);
      asm volatile("s_waitcnt vmcnt(%0)" :: "n"(2*CHT) : "memory");
    } else if (kk + 1 < nkk){
      asm volatile("s_waitcnt vmcnt(%0)" :: "n"(CHT) : "memory");
    } else {
      asm volatile("s_waitcnt vmcnt(0)" ::: "memory");
    }
    __builtin_amdgcn_sched_barrier(0);
    __builtin_amdgcn_s_barrier();
    __builtin_amdgcn_sched_barrier(0);
    const __bf16* Asb = &As[cur][0];
    const __bf16* Bsb = &Bs[cur][0];
    bf16x8 af[MI], bfr[NI];
    #pragma unroll
    for (int mi = 0; mi < MI; mi++) af[mi] = *(const bf16x8*)(Asb + (wm + mi*16 + lr)*32 + kb*8);
    #pragma unroll
    for (int ni = 0; ni < NI; ni++) bfr[ni] = *(const bf16x8*)(Bsb + (wn + ni*16 + lr)*32 + kb*8);
    #pragma unroll
    for (int mi = 0; mi < MI; mi++)
      #pragma unroll
      for (int ni = 0; ni < NI; ni++)
        acc[mi][ni] = __builtin_amdgcn_mfma_f32_16x16x32_bf16(af[mi], bfr[ni], acc[mi][ni], 0, 0, 0);
    __builtin_amdgcn_s_barrier();
    __builtin_amdgcn_sched_barrier(0);
  }
  #pragma unroll
  for (int mi = 0; mi < MI; mi++){
    #pragma unroll
    for (int ni = 0; ni < NI; ni++){
      int r0 = bm*BM + wm + mi*16 + (lane >> 4)*4;
      int c  = bn*BN + wn + ni*16 + lr;
      if (c < Nc){
        OutT* Cp = C + (size_t)r0*Nc + c;
        #pragma unroll
        for (int j = 0; j < 4; j++){
          float v = acc[mi][ni][j];
          if (EPI == 1){ float u = v + bias[c]; v = geluf(u); }
          if (EPI == 2){ v += (float)Cp[(size_t)j*Nc]; }
          Cp[(size_t)j*Nc] = (OutT)v;
        }
      }
    }
  }
}

/* ---------------- LayerNorm row(512) bf16 -> bf16 ---------------- */
__global__ __launch_bounds__(256) void ln_kernel(const __bf16* __restrict__ h, const float* __restrict__ w,
                                                 const float* __restrict__ b, __bf16* __restrict__ out){
  int row = blockIdx.x*4 + (threadIdx.x >> 6);
  int lane = threadIdx.x & 63;
  const __bf16* hr = h + (size_t)row*DMODEL + lane*8;
  bf16x8 a = *(const bf16x8*)hr;
  float v[8];
  #pragma unroll
  for (int i = 0; i < 8; i++) v[i] = (float)a[i];
  float s = 0.f;
  #pragma unroll
  for (int i = 0; i < 8; i++) s += v[i];
  #pragma unroll
  for (int o = 32; o; o >>= 1) s += __shfl_xor(s, o, 64);
  float mu = s*(1.f/512.f);
  float q = 0.f;
  #pragma unroll
  for (int i = 0; i < 8; i++){ float d = v[i]-mu; q += d*d; }
  #pragma unroll
  for (int o = 32; o; o >>= 1) q += __shfl_xor(q, o, 64);
  float rs = rsqrtf(q*(1.f/512.f) + 1e-5f);
  const float* wp = w + lane*8; const float* bp = b + lane*8;
  bf16x8 o8;
  #pragma unroll
  for (int i = 0; i < 8; i++) o8[i] = (__bf16)((v[i]-mu)*rs*wp[i] + bp[i]);
  *(bf16x8*)(out + (size_t)row*DMODEL + lane*8) = o8;
}

/* ---------------- merged conv+SiLU (vectorized, 8 ch/thread) and dt=softplus ---------------- */
__global__ __launch_bounds__(256) void convdt_kernel(const __bf16* __restrict__ zx, const float* __restrict__ cw,
                                                     const float* __restrict__ cb, const float* __restrict__ dt_bias,
                                                     __bf16* __restrict__ BCc, float* __restrict__ dtT){
  long idx = (long)blockIdx.x*256 + threadIdx.x;   /* ROWS*32 */
  long bt = idx >> 5;
  int j = (int)(idx & 31);
  if (bt >= ROWS) return;
  int t = (int)(bt & (SEQ-1));
  int b = (int)(bt >> 12);
  if (j < 16){
    /* conv+SiLU for channels [j*8, j*8+8) of the 128 B/C channels */
    int c0 = j*8;
    const __bf16* src = zx + (size_t)bt*DPROJ + 2048 + c0;
    bf16x8 v0 = *(const bf16x8*)src;
    bf16x8 v1, v2, v3;
    #pragma unroll
    for (int e = 0; e < 8; e++){ v1[e] = (__bf16)0.f; v2[e] = (__bf16)0.f; v3[e] = (__bf16)0.f; }
    if (t >= 1) v1 = *(const bf16x8*)(src - 1L*DPROJ);
    if (t >= 2) v2 = *(const bf16x8*)(src - 2L*DPROJ);
    if (t >= 3) v3 = *(const bf16x8*)(src - 3L*DPROJ);
    bf16x8 o;
    #pragma unroll
    for (int e = 0; e < 8; e++){
      int ch = DINNER + c0 + e;
      float acc = cb[ch] + (float)v0[e]*cw[ch*4+3] + (float)v1[e]*cw[ch*4+2]
                + (float)v2[e]*cw[ch*4+1] + (float)v3[e]*cw[ch*4+0];
      o[e] = (__bf16)siluf(acc);
    }
    *(bf16x8*)(BCc + (size_t)bt*128 + c0) = o;
  } else {
    int hh = j - 16;
    float v = (float)zx[(size_t)bt*DPROJ + (DPROJ-NH) + hh] + dt_bias[hh];
    float sp = (v > 20.f) ? v : log1pf(__expf(v));
    dtT[((size_t)b*NH + hh)*SEQ + t] = sp;
  }
}

/* ================= SSD kernel A — per-chunk state via MFMA (2 waves/block) ================= */
__global__ __launch_bounds__(128) void ssd_state(const __bf16* __restrict__ zx, const __bf16* __restrict__ BCc,
                                                 const float* __restrict__ dtT, const float* __restrict__ A_log,
                                                 const float* __restrict__ cw, const float* __restrict__ cb,
                                                 __bf16* __restrict__ Schunk, float* __restrict__ Pbuf,
                                                 __bf16* __restrict__ xhT){
  __shared__ __align__(16) __bf16 Bt_all[2][64*LD];
  __shared__ __align__(16) __bf16 Xt_all[2][64*LD];
  int widx = threadIdx.x >> 6, lane = threadIdx.x & 63;
  int c = blockIdx.x*2 + widx, h = blockIdx.y, b = blockIdx.z;
  __bf16* Bt = Bt_all[widx];
  __bf16* Xt = Xt_all[widx];
  int lr = lane & 15, kb = lane >> 4, hi4 = lane >> 4;
  long t0 = (long)c*QC;
  size_t bt0 = (size_t)b*SEQ + t0;
  int bh = b*NH + h;
  float Ac = -expf(A_log[h]);
  float dtv = dtT[(size_t)bh*SEQ + t0 + lane];
  float cum = dtv*Ac;
  #pragma unroll
  for (int off = 1; off < 64; off <<= 1){ float v = __shfl_up(cum, off, 64); if (lane >= off) cum += v; }
  float cumQ = __shfl(cum, 63, 64);
  float w = __expf(cumQ - cum) * dtv;
  {
    const __bf16* bp = BCc + bt0*128 + lane;
    for (int tb = 0; tb < 8; tb++){
      bf16x8 buf;
      #pragma unroll
      for (int u = 0; u < 8; u++){
        int t = tb*8 + u;
        float bv = (float)bp[(size_t)t*128];
        buf[u] = (__bf16)(bv * __shfl(w, t, 64));
      }
      *(bf16x8*)&Bt[lane*LD + tb*8] = buf;
    }
  }
  {
    int ch = h*HD + lane;
    float w0 = cw[ch*4], w1 = cw[ch*4+1], w2 = cw[ch*4+2], w3 = cw[ch*4+3], cbv = cb[ch];
    const __bf16* xp = zx + bt0*DPROJ + (DINNER + ch);
    float x1 = (t0 >= 1) ? (float)xp[-1L*DPROJ] : 0.f;
    float x2 = (t0 >= 2) ? (float)xp[-2L*DPROJ] : 0.f;
    float x3 = (t0 >= 3) ? (float)xp[-3L*DPROJ] : 0.f;
    __bf16* xo = xhT + ((size_t)bh*NCH + c)*4096 + lane*64;
    for (int tb = 0; tb < 8; tb++){
      bf16x8 buf;
      #pragma unroll
      for (int u = 0; u < 8; u++){
        int t = tb*8 + u;
        float x0 = (float)xp[(size_t)t*DPROJ];
        float xv = siluf(cbv + w3*x0 + w2*x1 + w1*x2 + w0*x3);
        x3 = x2; x2 = x1; x1 = x0;
        buf[u] = (__bf16)xv;
      }
      *(bf16x8*)&Xt[lane*LD + tb*8] = buf;
      *(bf16x8*)(xo + tb*8) = buf;
    }
  }
  f32x4 acc[4][4] = {};
  #pragma unroll
  for (int kk = 0; kk < 2; kk++){
    bf16x8 af[4], bfr[4];
    #pragma unroll
    for (int mi = 0; mi < 4; mi++) af[mi]  = *(bf16x8*)&Bt[(mi*16+lr)*LD + kk*32 + kb*8];
    #pragma unroll
    for (int ni = 0; ni < 4; ni++) bfr[ni] = *(bf16x8*)&Xt[(ni*16+lr)*LD + kk*32 + kb*8];
    #pragma unroll
    for (int mi = 0; mi < 4; mi++)
      #pragma unroll
      for (int ni = 0; ni < 4; ni++)
        acc[mi][ni] = __builtin_amdgcn_mfma_f32_16x16x32_bf16(af[mi], bfr[ni], acc[mi][ni], 0, 0, 0);
  }
  __bf16* Sp = Schunk + ((size_t)bh*NCH + c)*4096;
  #pragma unroll
  for (int mi = 0; mi < 4; mi++)
    #pragma unroll
    for (int ni = 0; ni < 4; ni++){
      int n0 = mi*16 + hi4*4;
      int p  = ni*16 + lr;
      bf16x4 v;
      #pragma unroll
      for (int r = 0; r < 4; r++) v[r] = (__bf16)acc[mi][ni][r];
      *(bf16x4*)&Sp[p*64 + n0] = v;
    }
  if (lane == 0) Pbuf[bh*NCH + c] = __expf(cumQ);
}

/* ========== in-place chunk-state -> prefix-state ========== */
__global__ __launch_bounds__(64) void ssd_comb(__bf16* __restrict__ Schunk, const float* __restrict__ Pbuf){
  int bh = blockIdx.x >> 4;
  int eb = blockIdx.x & 15;
  int e = eb*256 + threadIdx.x*4;
  __bf16* base = Schunk + (size_t)bh*NCH*4096 + e;
  float T0 = 0.f, T1 = 0.f, T2 = 0.f, T3 = 0.f;
  for (int c = 0; c < NCH; c++){
    float P = Pbuf[bh*NCH + c];
    bf16x4* p = (bf16x4*)(base + (size_t)c*4096);
    bf16x4 s = *p;
    bf16x4 o; o[0] = (__bf16)T0; o[1] = (__bf16)T1; o[2] = (__bf16)T2; o[3] = (__bf16)T3;
    *p = o;
    T0 = T0*P + (float)s[0]; T1 = T1*P + (float)s[1];
    T2 = T2*P + (float)s[2]; T3 = T3*P + (float)s[3];
  }
}

/* ================= SSD kernel B — outputs via MFMA (4 waves/block, per-wave LDS) ================= */
__global__ __launch_bounds__(256) void ssd_y(const __bf16* __restrict__ BCc, const float* __restrict__ dtT,
                                             const float* __restrict__ A_log, const float* __restrict__ Dskip,
                                             const __bf16* __restrict__ xhT, const __bf16* __restrict__ Spre,
                                             __bf16* __restrict__ yout){
  __shared__ __align__(16) __bf16 Gs_all[4][64*LD];
  __shared__ float cum_all[4][64], dt_all[4][64];
  int widx = threadIdx.x >> 6, lane = threadIdx.x & 63;
  int c = blockIdx.x*4 + widx, h = blockIdx.y, b = blockIdx.z;
  __bf16* Gs = Gs_all[widx];
  float* cum_s = cum_all[widx];
  float* dt_s = dt_all[widx];
  int lr = lane & 15, kb = lane >> 4, hi4 = lane >> 4;
  long t0 = (long)c*QC;
  size_t bt0 = (size_t)b*SEQ + t0;
  int bh = b*NH + h;
  float Ac = -expf(A_log[h]);
  float Dk = Dskip[h];
  float dtv = dtT[(size_t)bh*SEQ + t0 + lane];
  float cum = dtv*Ac;
  #pragma unroll
  for (int off = 1; off < 64; off <<= 1){ float v = __shfl_up(cum, off, 64); if (lane >= off) cum += v; }
  cum_s[lane] = cum; dt_s[lane] = dtv;
  bf16x8 cf[4][2];
  #pragma unroll
  for (int ni = 0; ni < 4; ni++)
    #pragma unroll
    for (int kk = 0; kk < 2; kk++)
      cf[ni][kk] = *(const bf16x8*)&BCc[(bt0 + ni*16 + lr)*128 + 64 + kk*32 + kb*8];
  f32x4 g[4][4] = {};
  #pragma unroll
  for (int kk = 0; kk < 2; kk++){
    bf16x8 bfj[4];
    #pragma unroll
    for (int mi = 0; mi < 4; mi++) bfj[mi] = *(const bf16x8*)&BCc[(bt0 + mi*16 + lr)*128 + kk*32 + kb*8];
    #pragma unroll
    for (int mi = 0; mi < 4; mi++)
      #pragma unroll
      for (int ni = 0; ni < 4; ni++)
        g[mi][ni] = __builtin_amdgcn_mfma_f32_16x16x32_bf16(bfj[mi], cf[ni][kk], g[mi][ni], 0, 0, 0);
  }
  float cumi[4];
  #pragma unroll
  for (int ni = 0; ni < 4; ni++) cumi[ni] = cum_s[ni*16 + lr];
  #pragma unroll
  for (int mi = 0; mi < 4; mi++){
    #pragma unroll
    for (int r = 0; r < 4; r++){
      int j = mi*16 + hi4*4 + r;
      float cj = cum_s[j], dj = dt_s[j];
      #pragma unroll
      for (int ni = 0; ni < 4; ni++){
        int i = ni*16 + lr;
        float v = g[mi][ni][r];
        if (i > j)       v = v * __expf(cumi[ni] - cj) * dj;
        else if (i == j) v = v*dj + Dk;
        else             v = 0.f;
        g[mi][ni][r] = v;
      }
    }
  }
  #pragma unroll
  for (int mi = 0; mi < 4; mi++)
    #pragma unroll
    for (int ni = 0; ni < 4; ni++){
      int j0 = mi*16 + hi4*4;
      int i  = ni*16 + lr;
      bf16x4 v;
      #pragma unroll
      for (int r = 0; r < 4; r++) v[r] = (__bf16)g[mi][ni][r];
      *(bf16x4*)&Gs[i*LD + j0] = v;
    }
  const __bf16* Xp = xhT + ((size_t)bh*NCH + c)*4096;
  f32x4 y4[4][4] = {};
  #pragma unroll
  for (int kk = 0; kk < 2; kk++){
    bf16x8 af2[4], bf2[4];
    #pragma unroll
    for (int mi = 0; mi < 4; mi++) af2[mi] = *(const bf16x8*)&Xp[(mi*16+lr)*64 + kk*32 + kb*8];
    #pragma unroll
    for (int ni = 0; ni < 4; ni++) bf2[ni] = *(bf16x8*)&Gs[(ni*16+lr)*LD + kk*32 + kb*8];
    #pragma unroll
    for (int mi = 0; mi < 4; mi++)
      #pragma unroll
      for (int ni = 0; ni < 4; ni++)
        y4[mi][ni] = __builtin_amdgcn_mfma_f32_16x16x32_bf16(af2[mi], bf2[ni], y4[mi][ni], 0, 0, 0);
  }
  {
    const __bf16* Sp = Spre + ((size_t)bh*NCH + c)*4096;
    float ei[4];
    #pragma unroll
    for (int ni = 0; ni < 4; ni++) ei[ni] = __expf(cumi[ni]);
    #pragma unroll
    for (int kk = 0; kk < 2; kk++){
      bf16x8 as1[4];
      #pragma unroll
      for (int mi = 0; mi < 4; mi++) as1[mi] = *(const bf16x8*)&Sp[(mi*16+lr)*64 + kk*32 + kb*8];
      #pragma unroll
      for (int ni = 0; ni < 4; ni++){
        bf16x8 cs = scale8(cf[ni][kk], ei[ni]);
        #pragma unroll
        for (int mi = 0; mi < 4; mi++)
          y4[mi][ni] = __builtin_amdgcn_mfma_f32_16x16x32_bf16(as1[mi], cs, y4[mi][ni], 0, 0, 0);
      }
    }
  }
  #pragma unroll
  for (int mi = 0; mi < 4; mi++)
    #pragma unroll
    for (int ni = 0; ni < 4; ni++){
      int p0 = mi*16 + hi4*4;
      int i  = ni*16 + lr;
      bf16x4 v;
      #pragma unroll
      for (int r = 0; r < 4; r++) v[r] = (__bf16)y4[mi][ni][r];
      *(bf16x4*)&yout[(bt0 + i)*DINNER + h*HD + p0] = v;
    }
}

/* ---------------- gate (silu(z)) + RMSNorm(1024), in-place on y (bf16) ---------------- */
__global__ __launch_bounds__(256) void gate_rms(__bf16* __restrict__ y, const __bf16* __restrict__ zx,
                                                const float* __restrict__ nw){
  int row = blockIdx.x*4 + (threadIdx.x >> 6);
  int lane = threadIdx.x & 63;
  __bf16* yr = y + (size_t)row*DINNER + lane*16;
  const __bf16* zr = zx + (size_t)row*DPROJ + lane*16;
  bf16x8 y0 = *(const bf16x8*)yr, y1 = *(const bf16x8*)(yr+8);
  bf16x8 z0 = *(const bf16x8*)zr, z1 = *(const bf16x8*)(zr+8);
  float v[16]; float ss = 0.f;
  #pragma unroll
  for (int i = 0; i < 8; i++){ float z = (float)z0[i]; float tv = (float)y0[i]*siluf(z); v[i] = tv; ss += tv*tv; }
  #pragma unroll
  for (int i = 0; i < 8; i++){ float z = (float)z1[i]; float tv = (float)y1[i]*siluf(z); v[8+i] = tv; ss += tv*tv; }
  #pragma unroll
  for (int o = 32; o; o >>= 1) ss += __shfl_xor(ss, o, 64);
  float rs = rsqrtf(ss*(1.f/1024.f) + 1e-5f);
  const float* np = nw + lane*16;
  bf16x8 o0, o1;
  #pragma unroll
  for (int i = 0; i < 8; i++){ o0[i] = (__bf16)(v[i]*rs*np[i]); o1[i] = (__bf16)(v[8+i]*rs*np[8+i]); }
  *(bf16x8*)yr = o0; *(bf16x8*)(yr+8) = o1;
}

/* ---------------- classifier (bf16 h) ---------------- */
__global__ __launch_bounds__(256) void cls_kernel(const __bf16* __restrict__ h, const float* __restrict__ Wc,
                                                  const float* __restrict__ bc, float* __restrict__ out){
  int row = blockIdx.x*4 + (threadIdx.x >> 6);
  int lane = threadIdx.x & 63;
  const __bf16* hr = h + (size_t)row*DMODEL + lane*8;
  bf16x8 a = *(const bf16x8*)hr;
  float hv[8];
  #pragma unroll
  for (int i = 0; i < 8; i++) hv[i] = (float)a[i];
  const float* w0 = Wc + lane*8;
  const float* w1 = Wc + DMODEL + lane*8;
  float s0 = 0.f, s1 = 0.f;
  #pragma unroll
  for (int i = 0; i < 8; i++){ s0 += hv[i]*w0[i]; s1 += hv[i]*w1[i]; }
  #pragma unroll
  for (int o = 32; o; o >>= 1){ s0 += __shfl_xor(s0, o, 64); s1 += __shfl_xor(s1, o, 64); }
  if (lane == 0){ out[(size_t)row*2] = s0 + bc[0]; out[(size_t)row*2 + 1] = s1 + bc[1]; }
}

extern "C" void kernel_launch(void* const* d_in, const int* in_sizes, int n_in,
                              void* d_out, int out_size, void* d_ws, size_t ws_size,
                              hipStream_t stream){
  const float* x       = (const float*)d_in[0];
  const float* W1      = (const float*)d_in[1];
  const float* b1      = (const float*)d_in[2];
  const float* ln_w    = (const float*)d_in[3];
  const float* ln_b    = (const float*)d_in[4];
  const float* W_in    = (const float*)d_in[5];
  const float* conv_w  = (const float*)d_in[6];
  const float* conv_b  = (const float*)d_in[7];
  const float* dt_bias = (const float*)d_in[8];
  const float* A_log   = (const float*)d_in[9];
  const float* Dskip   = (const float*)d_in[10];
  const float* norm_w  = (const float*)d_in[11];
  const float* W_out   = (const float*)d_in[12];
  const float* Wc      = (const float*)d_in[13];
  const float* bc      = (const float*)d_in[14];
  float* out = (float*)d_out;
  char* ws = (char*)d_ws;

  size_t off = 0;
  auto alloc = [&](size_t bytes){ void* p = ws + off; off += (bytes + 255) & ~(size_t)255; return p; };
  char*   regionA = (char*) alloc((size_t)ROWS*DIN*2);          /* x_bf -> hnb -> Schunk */
  __bf16* W1b     = (__bf16*)alloc((size_t)DMODEL*DIN*2);
  __bf16* Winb    = (__bf16*)alloc(2L*NPAD*DMODEL*2);
  __bf16* Woutb   = (__bf16*)alloc(2L*DMODEL*DINNER*2);
  __bf16* h       = (__bf16*)alloc((size_t)ROWS*DMODEL*2);
  __bf16* zx      = (__bf16*)alloc((size_t)ROWS*DPROJ*2);
  __bf16* BCc     = (__bf16*)alloc((size_t)ROWS*128*2);
  float*  dtT     = (float*) alloc((size_t)ROWS*NH*4);
  __bf16* ybuf    = (__bf16*)alloc((size_t)ROWS*DINNER*2);
  __bf16* xhT     = (__bf16*)alloc((size_t)ROWS*DINNER*2);
  float*  Pbuf    = (float*) alloc(64L*NCH*4);
  if (off > ws_size) return;   /* diagnostic: zero output instead of OOB crash */

  __bf16* x_bf   = (__bf16*)regionA;
  __bf16* hnb    = (__bf16*)regionA;
  __bf16* Schunk = (__bf16*)regionA;

  cast_bf16_kernel<<<2048, 256, 0, stream>>>(x, x_bf, (long)ROWS*DIN/8);
  prep_weights<<<1024, 256, 0, stream>>>(W1, W_out, W_in, W1b, Woutb, Winb);

  /* h = gelu(x @ W1^T + b1) : 64x128 (r12 config) */
  {
    dim3 g(ROWS/64, DMODEL/128);
    gemm_bt<__bf16,1,64,128><<<g, 256, 0, stream>>>(x_bf, W1b, h, b1, DIN, DMODEL);
  }

  for (int l = 0; l < 2; l++){
    ln_kernel<<<ROWS/4, 256, 0, stream>>>(h, ln_w + l*DMODEL, ln_b + l*DMODEL, hnb);
    {
      dim3 g(ROWS/128, NPAD/128);
      gemm_bt<__bf16,0,128,128><<<g, 256, 0, stream>>>(hnb, Winb + (size_t)l*NPAD*DMODEL, zx, nullptr, DMODEL, DPROJ);
    }
    convdt_kernel<<<(ROWS*32)/256, 256, 0, stream>>>(zx, conv_w + l*CONVDIM*4, conv_b + l*CONVDIM,
                                                     dt_bias + l*NH, BCc, dtT);
    {
      dim3 gs(NCH/2, NH, BATCH);
      ssd_state<<<gs, 128, 0, stream>>>(zx, BCc, dtT, A_log + l*NH,
                                        conv_w + l*CONVDIM*4, conv_b + l*CONVDIM, Schunk, Pbuf, xhT);
      ssd_comb<<<64*16, 64, 0, stream>>>(Schunk, Pbuf);
      dim3 gy(NCH/4, NH, BATCH);
      ssd_y<<<gy, 256, 0, stream>>>(BCc, dtT, A_log + l*NH, Dskip + l*NH, xhT, Schunk, ybuf);
    }
    gate_rms<<<ROWS/4, 256, 0, stream>>>(ybuf, zx, norm_w + l*DINNER);
    {
      dim3 g(ROWS/64, DMODEL/128);
      gemm_bt<__bf16,2,64,128><<<g, 256, 0, stream>>>(ybuf, Woutb + (size_t)l*DMODEL*DINNER, h, nullptr, DINNER, DMODEL);
    }
  }

  cls_kernel<<<ROWS/4, 256, 0, stream>>>(h, Wc, bc, out);
}